// Round 6
// baseline (215.671 us; speedup 1.0000x reference)
//
#include <hip/hip_runtime.h>

// RewardTripletLoss: sim/gram GEMMs (bf16 MFMA) + per-row loss + FastAP rewards.
// R9: revert R8 mask precompute (+8us regression: lossap insensitive to VMEM/
// compare count; mask kernel pure overhead). Back to R7 body plus:
//  (1) sim floats kept in VGPRs across pass1/pass2 (no re-unpack)
//  (2) fma-form binning: tt = clamp(fma(-800,s,800),0,1600) (~6 VALU/elem less)
//  (3) final_kernel folded into lossap: last-block-done pattern (workspace u32
//      counter + threadfence; NOT the R6 d_out-atomic trap which cost +17us)

#define N_ROWS 4096
#define DIM 128
#define TILE 128
#define L_BINS 1601

typedef __bf16 bf16x8 __attribute__((ext_vector_type(8)));
typedef float f32x4 __attribute__((ext_vector_type(4)));

__device__ __forceinline__ unsigned short f32_to_bf16(float f) {
    unsigned int u = __float_as_uint(f);
    u = (u + 0x7FFFu + ((u >> 16) & 1u)) >> 16;
    return (unsigned short)u;
}

__device__ __forceinline__ float bf16_lo(unsigned int u) {
    return __uint_as_float(u << 16);
}
__device__ __forceinline__ float bf16_hi(unsigned int u) {
    return __uint_as_float(u & 0xFFFF0000u);
}

__device__ __forceinline__ void unpack8(uint4 pk, float* s) {
    s[0] = bf16_lo(pk.x); s[1] = bf16_hi(pk.x);
    s[2] = bf16_lo(pk.y); s[3] = bf16_hi(pk.y);
    s[4] = bf16_lo(pk.z); s[5] = bf16_hi(pk.z);
    s[6] = bf16_lo(pk.w); s[7] = bf16_hi(pk.w);
}

// Async global->LDS, 16B per lane. LDS dest is wave-uniform base + lane*16.
__device__ __forceinline__ void async_copy16(const void* g, void* l) {
    __builtin_amdgcn_global_load_lds(
        (const __attribute__((address_space(1))) unsigned int*)g,
        (__attribute__((address_space(3))) unsigned int*)l, 16, 0, 0);
}

// Both f32->bf16 conversions in one launch. Zeroes the lossap done-counter.
__global__ __launch_bounds__(256) void cvt2_kernel(const float4* __restrict__ a,
                                                   const float4* __restrict__ b,
                                                   ushort4* __restrict__ oa,
                                                   ushort4* __restrict__ ob,
                                                   unsigned int* __restrict__ counter,
                                                   int nvec) {
    if (blockIdx.x == 0 && threadIdx.x == 0) *counter = 0u;
    for (int idx = blockIdx.x * 256 + threadIdx.x; idx < 2 * nvec; idx += gridDim.x * 256) {
        bool second = idx >= nvec;
        int k = second ? idx - nvec : idx;
        float4 v = second ? b[k] : a[k];
        ushort4 o;
        o.x = f32_to_bf16(v.x); o.y = f32_to_bf16(v.y);
        o.z = f32_to_bf16(v.z); o.w = f32_to_bf16(v.w);
        if (second) ob[k] = o; else oa[k] = o;
    }
}

// C[i][j] = sum_k A[i][k]*Bz[j][k]. Grid (32,32,2): z=0 -> B0->C0 (sim), z=1 -> B1->C1 (gram).
__global__ __launch_bounds__(256) void gemm_tile_kernel(const unsigned short* __restrict__ A,
                                                        const unsigned short* __restrict__ B0,
                                                        const unsigned short* __restrict__ B1,
                                                        unsigned short* __restrict__ C0,
                                                        unsigned short* __restrict__ C1,
                                                        int N) {
    __shared__ unsigned short As[TILE * DIM];  // 32 KB (tile contiguous in global)
    __shared__ unsigned short Bs[TILE * DIM];  // 32 KB
    int w = threadIdx.x >> 6;
    int lane = threadIdx.x & 63;
    int tm = blockIdx.y, tn = blockIdx.x;
    const unsigned short* B = blockIdx.z ? B1 : B0;
    unsigned short* C = blockIdx.z ? C1 : C0;

    const char* ga = (const char*)(A + (size_t)tm * TILE * DIM);
    const char* gb = (const char*)(B + (size_t)tn * TILE * DIM);
#pragma unroll
    for (int it = 0; it < 8; ++it) {
        int off = (w * 8 + it) * 1024;  // wave-chunk of 1KB (64 lanes x 16B)
        async_copy16(ga + off + lane * 16, (char*)As + off);
        async_copy16(gb + off + lane * 16, (char*)Bs + off);
    }
    __syncthreads();

    int wm = (w & 1) * 64;
    int wn = (w >> 1) * 64;
    int quad = lane >> 4;
    int l15 = lane & 15;

    f32x4 acc[4][4] = {};
#pragma unroll
    for (int kk = 0; kk < 4; ++kk) {
        int kb = kk * 32 + quad * 8;
        bf16x8 af[4], bfr[4];
#pragma unroll
        for (int mi = 0; mi < 4; ++mi)
            af[mi] = *(const bf16x8*)&As[(wm + mi * 16 + l15) * DIM + kb];
#pragma unroll
        for (int ni = 0; ni < 4; ++ni)
            bfr[ni] = *(const bf16x8*)&Bs[(wn + ni * 16 + l15) * DIM + kb];
#pragma unroll
        for (int mi = 0; mi < 4; ++mi)
#pragma unroll
            for (int ni = 0; ni < 4; ++ni)
                acc[mi][ni] = __builtin_amdgcn_mfma_f32_16x16x32_bf16(af[mi], bfr[ni], acc[mi][ni], 0, 0, 0);
    }

#pragma unroll
    for (int mi = 0; mi < 4; ++mi) {
        int row0 = tm * TILE + wm + mi * 16 + quad * 4;
#pragma unroll
        for (int ni = 0; ni < 4; ++ni) {
            int col = tn * TILE + wn + ni * 16 + l15;
#pragma unroll
            for (int r = 0; r < 4; ++r)
                C[(size_t)(row0 + r) * N + col] = f32_to_bf16(acc[mi][ni][r]);
        }
    }
}

// Merged loss + FastAP: one block per row i (R7 structure).
// Tail: last-finishing block reduces contrib[] and writes out[0] (one u32
// workspace atomic per block + release/acquire threadfences for cross-XCD
// visibility -- rocPRIM-style decoupled completion).
__global__ __launch_bounds__(256) void lossap_kernel(const unsigned short* __restrict__ sim,
                                                     const unsigned short* __restrict__ gram,
                                                     const int* __restrict__ tcol,
                                                     const int* __restrict__ trow,
                                                     const int* __restrict__ rlab,
                                                     float* __restrict__ contrib,
                                                     unsigned int* __restrict__ counter,
                                                     float* __restrict__ out,
                                                     int n) {
    __shared__ unsigned int histA[L_BINS];  // total weight (x65536 fixed point)
    __shared__ unsigned int histP[L_BINS];  // positive weight
    __shared__ unsigned long long wsum[4];
    __shared__ float pmx[4], nmx[4], lsum[4], apw[4];
    __shared__ int npw[4];
    __shared__ unsigned int lastFlag;
    int i = blockIdx.x;
    int t = threadIdx.x;
    int w = t >> 6, lane = t & 63;

    for (int b = t; b < L_BINS; b += 256) { histA[b] = 0u; histP[b] = 0u; }

    int myt = tcol[i];
    int li = rlab[i];
    const uint4* simv = (const uint4*)(sim + (size_t)i * n);
    const uint4* grav = (const uint4*)(gram + (size_t)i * n);
    const int4* trv = (const int4*)trow;
    const int4* rlv = (const int4*)rlab;

    // Issue ALL global loads up front (sim row, gram row, both label arrays).
    uint4 spk[2], gpk[2];
    int4 tl[4], rl[4];
#pragma unroll
    for (int vv = 0; vv < 2; ++vv) {
        int vi = vv * 256 + t;
        spk[vv] = simv[vi];
        gpk[vv] = grav[vi];
        tl[2 * vv] = trv[2 * vi];
        tl[2 * vv + 1] = trv[2 * vi + 1];
        rl[2 * vv] = rlv[2 * vi];
        rl[2 * vv + 1] = rlv[2 * vi + 1];
    }
    __syncthreads();  // hist zeroed; row loads in flight

    // MERGED phase: sim maxima/masks (VALU) + gram binning atomics (DS pipe).
    // sim floats stay in s16[] registers for reuse in pass 2.
    float s16[16];
    float pmax = -3e38f, nmax = -3e38f;
    unsigned int posm = 0, negm = 0;
    int npos = 0;
#pragma unroll
    for (int vv = 0; vv < 2; ++vv) {
        int vi = vv * 256 + t;
        unpack8(spk[vv], &s16[vv * 8]);
        {
            int lab[8] = {tl[2 * vv].x, tl[2 * vv].y, tl[2 * vv].z, tl[2 * vv].w,
                          tl[2 * vv + 1].x, tl[2 * vv + 1].y, tl[2 * vv + 1].z, tl[2 * vv + 1].w};
#pragma unroll
            for (int k = 0; k < 8; ++k) {
                int j = vi * 8 + k;
                int e = vv * 8 + k;
                bool same = (lab[k] == myt);
                bool posf = same && (j != i);
                if (posf) pmax = fmaxf(pmax, s16[e]);
                if (!same) nmax = fmaxf(nmax, s16[e]);
                posm |= ((unsigned int)posf) << e;
                negm |= ((unsigned int)(!same)) << e;
            }
        }
        {
            float g[8];
            unpack8(gpk[vv], g);
            int lab[8] = {rl[2 * vv].x, rl[2 * vv].y, rl[2 * vv].z, rl[2 * vv].w,
                          rl[2 * vv + 1].x, rl[2 * vv + 1].y, rl[2 * vv + 1].z, rl[2 * vv + 1].w};
#pragma unroll
            for (int k = 0; k < 8; ++k) {
                int j = vi * 8 + k;
                // tt = clamp((2-2g)*400, 0, 1600) == clamp(fma(-800,g,800), 0, 1600)
                float tt = fmaf(-800.f, g[k], 800.f);
                tt = fminf(fmaxf(tt, 0.f), 1600.f);
                float fl = floorf(tt);
                int i0 = (int)fl;
                int i1 = min(i0 + 1, L_BINS - 1);
                unsigned int w1 = (unsigned int)((tt - fl) * 65536.0f);
                unsigned int w0 = 65536u - w1;
                bool diag = (j == i);
                if (diag) { w0 = 0u; w1 = 0u; }
                bool posf = (lab[k] == li) && !diag;
                atomicAdd(&histA[i0], w0);
                atomicAdd(&histA[i1], w1);
                if (posf) {
                    atomicAdd(&histP[i0], w0);
                    atomicAdd(&histP[i1], w1);
                    npos += 1;
                }
            }
        }
    }

    // Wave maxima reduce (VALU, overlaps atomic drain).
#pragma unroll
    for (int off = 32; off > 0; off >>= 1) {
        pmax = fmaxf(pmax, __shfl_xor(pmax, off));
        nmax = fmaxf(nmax, __shfl_xor(nmax, off));
    }
    if (lane == 0) { pmx[w] = pmax; nmx[w] = nmax; }
    __syncthreads();  // atomics complete + wave maxima visible

    pmax = fmaxf(fmaxf(pmx[0], pmx[1]), fmaxf(pmx[2], pmx[3]));
    nmax = fmaxf(fmaxf(nmx[0], nmx[1]), fmaxf(nmx[2], nmx[3]));

    // Pass 2: loss sums from s16 registers.
    float thr_n = nmax + 0.1f;               // pos selected when sim < neg_max + margin
    float thr_p = fmaxf(0.6f, pmax) - 0.1f;  // neg selected when sim > thr
    float pl = 0.f, nl = 0.f;
#pragma unroll
    for (int e = 0; e < 16; ++e) {
        bool posf = (posm >> e) & 1u;
        bool negf = (negm >> e) & 1u;
        pl += (posf && s16[e] < thr_n) ? 1.f - s16[e] : 0.f;
        nl += (negf && s16[e] > thr_p) ? s16[e] : 0.f;
    }
    float tot = pl + nl;
#pragma unroll
    for (int off = 32; off > 0; off >>= 1) tot += __shfl_xor(tot, off);

    // Chunked scan: 7 bins/thread; shuffle inclusive scan of thread totals.
    // Pack (pos<<32)|all so one u64 scan covers both cumsums (no carry between
    // halves: total all-weight per row = 4095*65536 < 2^32).
    const int CH = 7;
    int base = t * CH;
    unsigned long long lc[CH];
    unsigned long long run = 0ull;
#pragma unroll
    for (int k = 0; k < CH; ++k) {
        int idx = base + k;
        unsigned long long h = (idx < L_BINS)
            ? (((unsigned long long)histP[idx] << 32) | (unsigned long long)histA[idx])
            : 0ull;
        run += h;
        lc[k] = run;
    }
    unsigned long long tsum = run;
    unsigned long long sc = tsum;
#pragma unroll
    for (int off = 1; off < 64; off <<= 1) {
        unsigned long long v2 = __shfl_up(sc, off);
        if (lane >= off) sc += v2;
    }
    if (lane == 63) wsum[w] = sc;
    if (lane == 0) lsum[w] = tot;
    __syncthreads();
    unsigned long long woff = 0ull;
    for (int ww = 0; ww < w; ++ww) woff += wsum[ww];
    unsigned long long throff = woff + sc - tsum;  // exclusive offset for this thread

    float ap = 0.f;
#pragma unroll
    for (int k = 0; k < CH; ++k) {
        int idx = base + k;
        if (idx < L_BINS) {
            unsigned int hp = histP[idx];
            if (hp) {
                unsigned long long cum = lc[k] + throff;
                unsigned int Hp = (unsigned int)(cum >> 32);
                unsigned int Ha = (unsigned int)cum;
                ap += (float)hp * (float)Hp / (float)Ha;
            }
        }
    }
#pragma unroll
    for (int off = 32; off > 0; off >>= 1) {
        ap += __shfl_xor(ap, off);
        npos += __shfl_xor(npos, off);
    }
    if (lane == 0) { apw[w] = ap; npw[w] = npos; }
    __syncthreads();

    // Tail: write contrib[i]; last block reduces and writes out[0].
    if (t == 0) {
        float loss_i = (pmax > -1e30f) ? (lsum[0] + lsum[1] + lsum[2] + lsum[3]) : 0.f;
        float A = apw[0] + apw[1] + apw[2] + apw[3];
        int np = npw[0] + npw[1] + npw[2] + npw[3];
        float reward = (np > 0) ? A * (1.0f / 65536.0f) / (float)np : 0.f;
        contrib[i] = loss_i * (1.f - reward);
        __threadfence();  // release: contrib store visible before count bump
        unsigned int prev = atomicAdd(counter, 1u);
        lastFlag = (prev == (unsigned int)gridDim.x - 1u) ? 1u : 0u;
    }
    __syncthreads();
    if (lastFlag) {
        __threadfence();  // acquire: see all other blocks' contrib stores
        float s = 0.f;
        for (int j = t; j < N_ROWS; j += 256)
            s += ((volatile const float*)contrib)[j];
#pragma unroll
        for (int off = 32; off > 0; off >>= 1) s += __shfl_xor(s, off);
        if (lane == 0) lsum[w] = s;
        __syncthreads();
        if (t == 0) out[0] = (lsum[0] + lsum[1] + lsum[2] + lsum[3]) * (1.0f / (float)N_ROWS);
    }
}

extern "C" void kernel_launch(void* const* d_in, const int* in_sizes, int n_in,
                              void* d_out, int out_size, void* d_ws, size_t ws_size,
                              hipStream_t stream) {
    const float* inputs_col = (const float*)d_in[0];
    const int* targets_col = (const int*)d_in[1];
    const float* inputs_row = (const float*)d_in[2];
    const int* targets_row = (const int*)d_in[3];
    const int* reward_labels = (const int*)d_in[4];
    float* out = (float*)d_out;

    const int n = N_ROWS, m = N_ROWS, d = DIM;
    char* ws = (char*)d_ws;
    const size_t MB = 1048576;
    unsigned short* simbuf = (unsigned short*)ws;                 // 32 MB
    unsigned short* grambuf = (unsigned short*)(ws + 32 * MB);    // 32 MB
    unsigned short* Abf = (unsigned short*)(ws + 64 * MB);        // 1 MB
    unsigned short* Rbf = (unsigned short*)(ws + 65 * MB);        // 1 MB
    float* contrib = (float*)(ws + 66 * MB);                      // 16 KB
    unsigned int* counter = (unsigned int*)(ws + 66 * MB + 16384);

    // 1) f32 -> bf16 (both arrays, one launch); zeroes done-counter
    cvt2_kernel<<<512, 256, 0, stream>>>((const float4*)inputs_col, (const float4*)inputs_row,
                                         (ushort4*)Abf, (ushort4*)Rbf, counter, n * d / 4);

    // 2) sim = col@row^T and gram = col@col^T in one launch
    dim3 ggrid(n / TILE, n / TILE, 2);
    gemm_tile_kernel<<<ggrid, 256, 0, stream>>>(Abf, Rbf, Abf, simbuf, grambuf, m);

    // 3) merged per-row loss + FastAP reward -> contrib[i]; last block -> out[0]
    lossap_kernel<<<n, 256, 0, stream>>>(simbuf, grambuf, targets_col, targets_row,
                                         reward_labels, contrib, counter, out, n);
}

// Round 7
// 132.335 us; speedup vs baseline: 1.6297x; 1.6297x over previous
//
#include <hip/hip_runtime.h>

// RewardTripletLoss: sim/gram GEMMs (bf16 MFMA) + per-row loss + FastAP rewards.
// R10: revert R9 entirely (last-block tail: per-block threadfence + same-line
// global RMW serialized -> lossap 40->128us; s16 array scratch risk). Back to
// the R7 body with ONE variable changed: lossap block 256->512 threads
// (8 elems/thread). Halves every per-thread serial chain (load->use, binning,
// pass2, scan CH 7->4); wave residency/CU unchanged (32-wave cap: 4x8 vs 8x4);
// LDS 13KB not limiting. Pure latency-chain experiment.

#define N_ROWS 4096
#define DIM 128
#define TILE 128
#define L_BINS 1601

typedef __bf16 bf16x8 __attribute__((ext_vector_type(8)));
typedef float f32x4 __attribute__((ext_vector_type(4)));

__device__ __forceinline__ unsigned short f32_to_bf16(float f) {
    unsigned int u = __float_as_uint(f);
    u = (u + 0x7FFFu + ((u >> 16) & 1u)) >> 16;
    return (unsigned short)u;
}

__device__ __forceinline__ float bf16_lo(unsigned int u) {
    return __uint_as_float(u << 16);
}
__device__ __forceinline__ float bf16_hi(unsigned int u) {
    return __uint_as_float(u & 0xFFFF0000u);
}

__device__ __forceinline__ void unpack8(uint4 pk, float* s) {
    s[0] = bf16_lo(pk.x); s[1] = bf16_hi(pk.x);
    s[2] = bf16_lo(pk.y); s[3] = bf16_hi(pk.y);
    s[4] = bf16_lo(pk.z); s[5] = bf16_hi(pk.z);
    s[6] = bf16_lo(pk.w); s[7] = bf16_hi(pk.w);
}

// Async global->LDS, 16B per lane. LDS dest is wave-uniform base + lane*16.
__device__ __forceinline__ void async_copy16(const void* g, void* l) {
    __builtin_amdgcn_global_load_lds(
        (const __attribute__((address_space(1))) unsigned int*)g,
        (__attribute__((address_space(3))) unsigned int*)l, 16, 0, 0);
}

// Both f32->bf16 conversions in one launch.
__global__ __launch_bounds__(256) void cvt2_kernel(const float4* __restrict__ a,
                                                   const float4* __restrict__ b,
                                                   ushort4* __restrict__ oa,
                                                   ushort4* __restrict__ ob,
                                                   int nvec) {
    for (int idx = blockIdx.x * 256 + threadIdx.x; idx < 2 * nvec; idx += gridDim.x * 256) {
        bool second = idx >= nvec;
        int k = second ? idx - nvec : idx;
        float4 v = second ? b[k] : a[k];
        ushort4 o;
        o.x = f32_to_bf16(v.x); o.y = f32_to_bf16(v.y);
        o.z = f32_to_bf16(v.z); o.w = f32_to_bf16(v.w);
        if (second) ob[k] = o; else oa[k] = o;
    }
}

// C[i][j] = sum_k A[i][k]*Bz[j][k]. Grid (32,32,2): z=0 -> B0->C0 (sim), z=1 -> B1->C1 (gram).
__global__ __launch_bounds__(256) void gemm_tile_kernel(const unsigned short* __restrict__ A,
                                                        const unsigned short* __restrict__ B0,
                                                        const unsigned short* __restrict__ B1,
                                                        unsigned short* __restrict__ C0,
                                                        unsigned short* __restrict__ C1,
                                                        int N) {
    __shared__ unsigned short As[TILE * DIM];  // 32 KB (tile contiguous in global)
    __shared__ unsigned short Bs[TILE * DIM];  // 32 KB
    int w = threadIdx.x >> 6;
    int lane = threadIdx.x & 63;
    int tm = blockIdx.y, tn = blockIdx.x;
    const unsigned short* B = blockIdx.z ? B1 : B0;
    unsigned short* C = blockIdx.z ? C1 : C0;

    const char* ga = (const char*)(A + (size_t)tm * TILE * DIM);
    const char* gb = (const char*)(B + (size_t)tn * TILE * DIM);
#pragma unroll
    for (int it = 0; it < 8; ++it) {
        int off = (w * 8 + it) * 1024;  // wave-chunk of 1KB (64 lanes x 16B)
        async_copy16(ga + off + lane * 16, (char*)As + off);
        async_copy16(gb + off + lane * 16, (char*)Bs + off);
    }
    __syncthreads();

    int wm = (w & 1) * 64;
    int wn = (w >> 1) * 64;
    int quad = lane >> 4;
    int l15 = lane & 15;

    f32x4 acc[4][4] = {};
#pragma unroll
    for (int kk = 0; kk < 4; ++kk) {
        int kb = kk * 32 + quad * 8;
        bf16x8 af[4], bfr[4];
#pragma unroll
        for (int mi = 0; mi < 4; ++mi)
            af[mi] = *(const bf16x8*)&As[(wm + mi * 16 + l15) * DIM + kb];
#pragma unroll
        for (int ni = 0; ni < 4; ++ni)
            bfr[ni] = *(const bf16x8*)&Bs[(wn + ni * 16 + l15) * DIM + kb];
#pragma unroll
        for (int mi = 0; mi < 4; ++mi)
#pragma unroll
            for (int ni = 0; ni < 4; ++ni)
                acc[mi][ni] = __builtin_amdgcn_mfma_f32_16x16x32_bf16(af[mi], bfr[ni], acc[mi][ni], 0, 0, 0);
    }

#pragma unroll
    for (int mi = 0; mi < 4; ++mi) {
        int row0 = tm * TILE + wm + mi * 16 + quad * 4;
#pragma unroll
        for (int ni = 0; ni < 4; ++ni) {
            int col = tn * TILE + wn + ni * 16 + l15;
#pragma unroll
            for (int r = 0; r < 4; ++r)
                C[(size_t)(row0 + r) * N + col] = f32_to_bf16(acc[mi][ni][r]);
        }
    }
}

// Merged loss + FastAP: one 512-thread block per row i; 8 elems/thread.
// Phase structure (R7): zero hist + issue loads -> bar ; merged sim-maxima
// (VALU) + gram binning atomics (DS) ; wave maxima -> bar ; pass2 + scan
// (CH=4) -> bar ; AP + tail. Plain store to workspace contrib[].
__global__ __launch_bounds__(512) void lossap_kernel(const unsigned short* __restrict__ sim,
                                                     const unsigned short* __restrict__ gram,
                                                     const int* __restrict__ tcol,
                                                     const int* __restrict__ trow,
                                                     const int* __restrict__ rlab,
                                                     float* __restrict__ contrib,
                                                     int n) {
    __shared__ unsigned int histA[L_BINS];  // total weight (x65536 fixed point)
    __shared__ unsigned int histP[L_BINS];  // positive weight
    __shared__ unsigned long long wsum[8];
    __shared__ float pmx[8], nmx[8], lsum[8], apw[8];
    __shared__ int npw[8];
    int i = blockIdx.x;
    int t = threadIdx.x;
    int w = t >> 6, lane = t & 63;

    for (int b = t; b < L_BINS; b += 512) { histA[b] = 0u; histP[b] = 0u; }

    int myt = tcol[i];
    int li = rlab[i];
    const uint4* simv = (const uint4*)(sim + (size_t)i * n);
    const uint4* grav = (const uint4*)(gram + (size_t)i * n);
    const int4* trv = (const int4*)trow;
    const int4* rlv = (const int4*)rlab;

    // Issue ALL global loads up front (sim row, gram row, both label arrays).
    uint4 spk = simv[t];
    uint4 gpk = grav[t];
    int4 tl0 = trv[2 * t], tl1 = trv[2 * t + 1];
    int4 rl0 = rlv[2 * t], rl1 = rlv[2 * t + 1];
    __syncthreads();  // hist zeroed; row loads in flight

    // MERGED phase: sim maxima/masks (VALU) + gram binning atomics (DS pipe).
    float pmax = -3e38f, nmax = -3e38f;
    unsigned int posm = 0, negm = 0;
    int npos = 0;
    {
        float s[8];
        unpack8(spk, s);
        int lab[8] = {tl0.x, tl0.y, tl0.z, tl0.w, tl1.x, tl1.y, tl1.z, tl1.w};
#pragma unroll
        for (int k = 0; k < 8; ++k) {
            int j = t * 8 + k;
            bool same = (lab[k] == myt);
            bool posf = same && (j != i);
            if (posf) pmax = fmaxf(pmax, s[k]);
            if (!same) nmax = fmaxf(nmax, s[k]);
            posm |= ((unsigned int)posf) << k;
            negm |= ((unsigned int)(!same)) << k;
        }
    }
    {
        float g[8];
        unpack8(gpk, g);
        int lab[8] = {rl0.x, rl0.y, rl0.z, rl0.w, rl1.x, rl1.y, rl1.z, rl1.w};
#pragma unroll
        for (int k = 0; k < 8; ++k) {
            int j = t * 8 + k;
            float d2 = fminf(fmaxf(2.f - 2.f * g[k], 0.f), 4.f);
            float tt = d2 * 400.0f;  // / (4/1600)
            float fl = floorf(tt);
            int i0 = (int)fl;
            if (i0 > L_BINS - 1) i0 = L_BINS - 1;
            int i1 = i0 + 1;
            if (i1 > L_BINS - 1) i1 = L_BINS - 1;
            unsigned int w1 = (unsigned int)((tt - fl) * 65536.0f);
            unsigned int w0 = 65536u - w1;
            bool diag = (j == i);
            if (diag) { w0 = 0u; w1 = 0u; }
            bool posf = (lab[k] == li) && !diag;
            atomicAdd(&histA[i0], w0);
            atomicAdd(&histA[i1], w1);
            if (posf) {
                atomicAdd(&histP[i0], w0);
                atomicAdd(&histP[i1], w1);
                npos += 1;
            }
        }
    }

    // Wave maxima reduce (VALU, overlaps atomic drain).
#pragma unroll
    for (int off = 32; off > 0; off >>= 1) {
        pmax = fmaxf(pmax, __shfl_xor(pmax, off));
        nmax = fmaxf(nmax, __shfl_xor(nmax, off));
    }
    if (lane == 0) { pmx[w] = pmax; nmx[w] = nmax; }
    __syncthreads();  // atomics complete + wave maxima visible

    pmax = fmaxf(fmaxf(fmaxf(pmx[0], pmx[1]), fmaxf(pmx[2], pmx[3])),
                 fmaxf(fmaxf(pmx[4], pmx[5]), fmaxf(pmx[6], pmx[7])));
    nmax = fmaxf(fmaxf(fmaxf(nmx[0], nmx[1]), fmaxf(nmx[2], nmx[3])),
                 fmaxf(fmaxf(nmx[4], nmx[5]), fmaxf(nmx[6], nmx[7])));

    // Pass 2: loss sums from registers.
    float thr_n = nmax + 0.1f;               // pos selected when sim < neg_max + margin
    float thr_p = fmaxf(0.6f, pmax) - 0.1f;  // neg selected when sim > thr
    float pl = 0.f, nl = 0.f;
    {
        float s[8];
        unpack8(spk, s);
#pragma unroll
        for (int k = 0; k < 8; ++k) {
            bool posf = (posm >> k) & 1u;
            bool negf = (negm >> k) & 1u;
            pl += (posf && s[k] < thr_n) ? 1.f - s[k] : 0.f;
            nl += (negf && s[k] > thr_p) ? s[k] : 0.f;
        }
    }
    float tot = pl + nl;
#pragma unroll
    for (int off = 32; off > 0; off >>= 1) tot += __shfl_xor(tot, off);

    // Chunked scan: 4 bins/thread; shuffle inclusive scan of thread totals.
    // Pack (pos<<32)|all so one u64 scan covers both cumsums (no carry between
    // halves: total all-weight per row = 4095*65536 < 2^32).
    const int CH = 4;
    int base = t * CH;
    unsigned long long lc[CH];
    unsigned long long run = 0ull;
#pragma unroll
    for (int k = 0; k < CH; ++k) {
        int idx = base + k;
        unsigned long long h = (idx < L_BINS)
            ? (((unsigned long long)histP[idx] << 32) | (unsigned long long)histA[idx])
            : 0ull;
        run += h;
        lc[k] = run;
    }
    unsigned long long tsum = run;
    unsigned long long sc = tsum;
#pragma unroll
    for (int off = 1; off < 64; off <<= 1) {
        unsigned long long v2 = __shfl_up(sc, off);
        if (lane >= off) sc += v2;
    }
    if (lane == 63) wsum[w] = sc;
    if (lane == 0) lsum[w] = tot;
    __syncthreads();
    unsigned long long woff = 0ull;
    for (int ww = 0; ww < w; ++ww) woff += wsum[ww];
    unsigned long long throff = woff + sc - tsum;  // exclusive offset for this thread

    float ap = 0.f;
#pragma unroll
    for (int k = 0; k < CH; ++k) {
        int idx = base + k;
        if (idx < L_BINS) {
            unsigned int hp = histP[idx];
            if (hp) {
                unsigned long long cum = lc[k] + throff;
                unsigned int Hp = (unsigned int)(cum >> 32);
                unsigned int Ha = (unsigned int)cum;
                ap += (float)hp * (float)Hp / (float)Ha;
            }
        }
    }
#pragma unroll
    for (int off = 32; off > 0; off >>= 1) {
        ap += __shfl_xor(ap, off);
        npos += __shfl_xor(npos, off);
    }
    if (lane == 0) { apw[w] = ap; npw[w] = npos; }
    __syncthreads();
    if (t == 0) {
        float loss_i = (pmax > -1e30f)
            ? (lsum[0] + lsum[1] + lsum[2] + lsum[3] + lsum[4] + lsum[5] + lsum[6] + lsum[7])
            : 0.f;
        float A = apw[0] + apw[1] + apw[2] + apw[3] + apw[4] + apw[5] + apw[6] + apw[7];
        int np = npw[0] + npw[1] + npw[2] + npw[3] + npw[4] + npw[5] + npw[6] + npw[7];
        float reward = (np > 0) ? A * (1.0f / 65536.0f) / (float)np : 0.f;
        contrib[i] = loss_i * (1.f - reward);
    }
}

__global__ __launch_bounds__(256) void final_kernel(const float* __restrict__ contrib,
                                                    float* __restrict__ out, int n) {
    __shared__ float r[256];
    int t = threadIdx.x;
    float s = 0.f;
    for (int j = t; j < n; j += 256) s += contrib[j];
    r[t] = s;
    __syncthreads();
    for (int off = 128; off > 0; off >>= 1) {
        if (t < off) r[t] += r[t + off];
        __syncthreads();
    }
    if (t == 0) out[0] = r[0] / (float)n;
}

extern "C" void kernel_launch(void* const* d_in, const int* in_sizes, int n_in,
                              void* d_out, int out_size, void* d_ws, size_t ws_size,
                              hipStream_t stream) {
    const float* inputs_col = (const float*)d_in[0];
    const int* targets_col = (const int*)d_in[1];
    const float* inputs_row = (const float*)d_in[2];
    const int* targets_row = (const int*)d_in[3];
    const int* reward_labels = (const int*)d_in[4];
    float* out = (float*)d_out;

    const int n = N_ROWS, m = N_ROWS, d = DIM;
    char* ws = (char*)d_ws;
    const size_t MB = 1048576;
    unsigned short* simbuf = (unsigned short*)ws;                 // 32 MB
    unsigned short* grambuf = (unsigned short*)(ws + 32 * MB);    // 32 MB
    unsigned short* Abf = (unsigned short*)(ws + 64 * MB);        // 1 MB
    unsigned short* Rbf = (unsigned short*)(ws + 65 * MB);        // 1 MB
    float* contrib = (float*)(ws + 66 * MB);                      // 16 KB

    // 1) f32 -> bf16 (both arrays, one launch)
    cvt2_kernel<<<512, 256, 0, stream>>>((const float4*)inputs_col, (const float4*)inputs_row,
                                         (ushort4*)Abf, (ushort4*)Rbf, n * d / 4);

    // 2) sim = col@row^T and gram = col@col^T in one launch
    dim3 ggrid(n / TILE, n / TILE, 2);
    gemm_tile_kernel<<<ggrid, 256, 0, stream>>>(Abf, Rbf, Abf, simbuf, grambuf, m);

    // 3) merged per-row loss + FastAP reward -> contrib[i] (512 thr/block)
    lossap_kernel<<<n, 512, 0, stream>>>(simbuf, grambuf, targets_col, targets_row,
                                         reward_labels, contrib, n);

    // 4) final scalar
    final_kernel<<<1, 256, 0, stream>>>(contrib, out, n);
}

// Round 8
// 123.579 us; speedup vs baseline: 1.7452x; 1.0709x over previous
//
#include <hip/hip_runtime.h>

// RewardTripletLoss: sim/gram GEMMs (bf16 MFMA) + per-row loss + FastAP rewards.
// R11: consolidation. Exact R5 body (best: 124.8us) + one safe delta: fma-form
// binning (clamp(fma(-800,s,800),0,1600); ~4 VALU/elem less, ULP-equivalent
// under the existing 2^-16 fixed-point quantization). Ledger of nulls/regressions:
// atomic width (R5 vs R4), d_out atomics (R6 +17us), phase merge (R7 0),
// mask precompute (R8 +8), fence tail (R9 +90), 512-thr blocks (R10 +7).
// lossap ~40-45us = mixed VALU/DS equilibrium; fill 46us = harness, at HBM roofline.

#define N_ROWS 4096
#define DIM 128
#define TILE 128
#define L_BINS 1601

typedef __bf16 bf16x8 __attribute__((ext_vector_type(8)));
typedef float f32x4 __attribute__((ext_vector_type(4)));

__device__ __forceinline__ unsigned short f32_to_bf16(float f) {
    unsigned int u = __float_as_uint(f);
    u = (u + 0x7FFFu + ((u >> 16) & 1u)) >> 16;
    return (unsigned short)u;
}

__device__ __forceinline__ float bf16_lo(unsigned int u) {
    return __uint_as_float(u << 16);
}
__device__ __forceinline__ float bf16_hi(unsigned int u) {
    return __uint_as_float(u & 0xFFFF0000u);
}

__device__ __forceinline__ void unpack8(uint4 pk, float* s) {
    s[0] = bf16_lo(pk.x); s[1] = bf16_hi(pk.x);
    s[2] = bf16_lo(pk.y); s[3] = bf16_hi(pk.y);
    s[4] = bf16_lo(pk.z); s[5] = bf16_hi(pk.z);
    s[6] = bf16_lo(pk.w); s[7] = bf16_hi(pk.w);
}

// Async global->LDS, 16B per lane. LDS dest is wave-uniform base + lane*16.
__device__ __forceinline__ void async_copy16(const void* g, void* l) {
    __builtin_amdgcn_global_load_lds(
        (const __attribute__((address_space(1))) unsigned int*)g,
        (__attribute__((address_space(3))) unsigned int*)l, 16, 0, 0);
}

// Both f32->bf16 conversions in one launch.
__global__ __launch_bounds__(256) void cvt2_kernel(const float4* __restrict__ a,
                                                   const float4* __restrict__ b,
                                                   ushort4* __restrict__ oa,
                                                   ushort4* __restrict__ ob,
                                                   int nvec) {
    for (int idx = blockIdx.x * 256 + threadIdx.x; idx < 2 * nvec; idx += gridDim.x * 256) {
        bool second = idx >= nvec;
        int k = second ? idx - nvec : idx;
        float4 v = second ? b[k] : a[k];
        ushort4 o;
        o.x = f32_to_bf16(v.x); o.y = f32_to_bf16(v.y);
        o.z = f32_to_bf16(v.z); o.w = f32_to_bf16(v.w);
        if (second) ob[k] = o; else oa[k] = o;
    }
}

// C[i][j] = sum_k A[i][k]*Bz[j][k]. Grid (32,32,2): z=0 -> B0->C0 (sim), z=1 -> B1->C1 (gram).
__global__ __launch_bounds__(256) void gemm_tile_kernel(const unsigned short* __restrict__ A,
                                                        const unsigned short* __restrict__ B0,
                                                        const unsigned short* __restrict__ B1,
                                                        unsigned short* __restrict__ C0,
                                                        unsigned short* __restrict__ C1,
                                                        int N) {
    __shared__ unsigned short As[TILE * DIM];  // 32 KB (tile contiguous in global)
    __shared__ unsigned short Bs[TILE * DIM];  // 32 KB
    int w = threadIdx.x >> 6;
    int lane = threadIdx.x & 63;
    int tm = blockIdx.y, tn = blockIdx.x;
    const unsigned short* B = blockIdx.z ? B1 : B0;
    unsigned short* C = blockIdx.z ? C1 : C0;

    const char* ga = (const char*)(A + (size_t)tm * TILE * DIM);
    const char* gb = (const char*)(B + (size_t)tn * TILE * DIM);
#pragma unroll
    for (int it = 0; it < 8; ++it) {
        int off = (w * 8 + it) * 1024;  // wave-chunk of 1KB (64 lanes x 16B)
        async_copy16(ga + off + lane * 16, (char*)As + off);
        async_copy16(gb + off + lane * 16, (char*)Bs + off);
    }
    __syncthreads();

    int wm = (w & 1) * 64;
    int wn = (w >> 1) * 64;
    int quad = lane >> 4;
    int l15 = lane & 15;

    f32x4 acc[4][4] = {};
#pragma unroll
    for (int kk = 0; kk < 4; ++kk) {
        int kb = kk * 32 + quad * 8;
        bf16x8 af[4], bfr[4];
#pragma unroll
        for (int mi = 0; mi < 4; ++mi)
            af[mi] = *(const bf16x8*)&As[(wm + mi * 16 + l15) * DIM + kb];
#pragma unroll
        for (int ni = 0; ni < 4; ++ni)
            bfr[ni] = *(const bf16x8*)&Bs[(wn + ni * 16 + l15) * DIM + kb];
#pragma unroll
        for (int mi = 0; mi < 4; ++mi)
#pragma unroll
            for (int ni = 0; ni < 4; ++ni)
                acc[mi][ni] = __builtin_amdgcn_mfma_f32_16x16x32_bf16(af[mi], bfr[ni], acc[mi][ni], 0, 0, 0);
    }

#pragma unroll
    for (int mi = 0; mi < 4; ++mi) {
        int row0 = tm * TILE + wm + mi * 16 + quad * 4;
#pragma unroll
        for (int ni = 0; ni < 4; ++ni) {
            int col = tn * TILE + wn + ni * 16 + l15;
#pragma unroll
            for (int r = 0; r < 4; ++r)
                C[(size_t)(row0 + r) * N + col] = f32_to_bf16(acc[mi][ni][r]);
        }
    }
}

// Merged loss + FastAP: one block per row i (R5 structure, best measured).
// - loss: 16 sim elems/thread register-resident; block max via shfl + LDS;
//   second pass from registers. (VALU + HBM pipe)
// - fastap: two u32 histograms. hist_all: 2 u32 atomics/elem (2-way bank floor,
//   free). hist_pos: exec-masked, ~8 elems/row. Scan packs (pos<<32)|all.
// 4 barriers total. Emits contrib[i] = loss_i * (1 - reward_i) (plain store).
__global__ __launch_bounds__(256) void lossap_kernel(const unsigned short* __restrict__ sim,
                                                     const unsigned short* __restrict__ gram,
                                                     const int* __restrict__ tcol,
                                                     const int* __restrict__ trow,
                                                     const int* __restrict__ rlab,
                                                     float* __restrict__ contrib,
                                                     int n) {
    __shared__ unsigned int histA[L_BINS];  // total weight (x65536 fixed point)
    __shared__ unsigned int histP[L_BINS];  // positive weight
    __shared__ unsigned long long wsum[4];
    __shared__ float pmx[4], nmx[4], lsum[4], apw[4];
    __shared__ int npw[4];
    int i = blockIdx.x;
    int t = threadIdx.x;
    int w = t >> 6, lane = t & 63;

    for (int b = t; b < L_BINS; b += 256) { histA[b] = 0u; histP[b] = 0u; }

    int myt = tcol[i];
    int li = rlab[i];
    const uint4* simv = (const uint4*)(sim + (size_t)i * n);
    const uint4* grav = (const uint4*)(gram + (size_t)i * n);
    const int4* trv = (const int4*)trow;
    const int4* rlv = (const int4*)rlab;

    // Issue ALL global loads up front (sim row, gram row, both label arrays)
    // so HBM latency hides under hist-zero + maxima pass.
    uint4 spk[2], gpk[2];
    int4 tl[4], rl[4];
#pragma unroll
    for (int vv = 0; vv < 2; ++vv) {
        int vi = vv * 256 + t;
        spk[vv] = simv[vi];
        gpk[vv] = grav[vi];
        tl[2 * vv] = trv[2 * vi];
        tl[2 * vv + 1] = trv[2 * vi + 1];
        rl[2 * vv] = rlv[2 * vi];
        rl[2 * vv + 1] = rlv[2 * vi + 1];
    }

    // Pass 1: per-thread pos/neg maxima + selection masks from sim.
    float pmax = -3e38f, nmax = -3e38f;
    unsigned int posm = 0, negm = 0;
#pragma unroll
    for (int vv = 0; vv < 2; ++vv) {
        int vi = vv * 256 + t;
        float s[8];
        unpack8(spk[vv], s);
        int lab[8] = {tl[2 * vv].x, tl[2 * vv].y, tl[2 * vv].z, tl[2 * vv].w,
                      tl[2 * vv + 1].x, tl[2 * vv + 1].y, tl[2 * vv + 1].z, tl[2 * vv + 1].w};
#pragma unroll
        for (int k = 0; k < 8; ++k) {
            int j = vi * 8 + k;
            bool same = (lab[k] == myt);
            bool posf = same && (j != i);
            if (posf) pmax = fmaxf(pmax, s[k]);
            if (!same) nmax = fmaxf(nmax, s[k]);
            posm |= ((unsigned int)posf) << (vv * 8 + k);
            negm |= ((unsigned int)(!same)) << (vv * 8 + k);
        }
    }
    __syncthreads();  // hist zeroed

    // FastAP histogram: 2 u32 atomics/elem (+ rare exec-masked pos atomics).
    int npos = 0;
#pragma unroll
    for (int vv = 0; vv < 2; ++vv) {
        int vi = vv * 256 + t;
        float g[8];
        unpack8(gpk[vv], g);
        int lab[8] = {rl[2 * vv].x, rl[2 * vv].y, rl[2 * vv].z, rl[2 * vv].w,
                      rl[2 * vv + 1].x, rl[2 * vv + 1].y, rl[2 * vv + 1].z, rl[2 * vv + 1].w};
#pragma unroll
        for (int k = 0; k < 8; ++k) {
            int j = vi * 8 + k;
            // tt = clamp((2-2g)*400,0,1600) == clamp(fma(-800,g,800),0,1600)
            float tt = fminf(fmaxf(fmaf(-800.f, g[k], 800.f), 0.f), 1600.f);
            float fl = floorf(tt);
            int i0 = (int)fl;
            int i1 = min(i0 + 1, L_BINS - 1);
            unsigned int w1 = (unsigned int)((tt - fl) * 65536.0f);
            unsigned int w0 = 65536u - w1;
            bool diag = (j == i);
            if (diag) { w0 = 0u; w1 = 0u; }
            bool posf = (lab[k] == li) && !diag;
            atomicAdd(&histA[i0], w0);
            atomicAdd(&histA[i1], w1);
            if (posf) {
                atomicAdd(&histP[i0], w0);
                atomicAdd(&histP[i1], w1);
                npos += 1;
            }
        }
    }

    // Wave maxima reduce (VALU, overlaps atomic drain).
#pragma unroll
    for (int off = 32; off > 0; off >>= 1) {
        pmax = fmaxf(pmax, __shfl_xor(pmax, off));
        nmax = fmaxf(nmax, __shfl_xor(nmax, off));
    }
    if (lane == 0) { pmx[w] = pmax; nmx[w] = nmax; }
    __syncthreads();  // atomics complete + wave maxima visible

    pmax = fmaxf(fmaxf(pmx[0], pmx[1]), fmaxf(pmx[2], pmx[3]));
    nmax = fmaxf(fmaxf(nmx[0], nmx[1]), fmaxf(nmx[2], nmx[3]));

    // Pass 2: loss sums from registers.
    float thr_n = nmax + 0.1f;               // pos selected when sim < neg_max + margin
    float thr_p = fmaxf(0.6f, pmax) - 0.1f;  // neg selected when sim > thr
    float pl = 0.f, nl = 0.f;
#pragma unroll
    for (int vv = 0; vv < 2; ++vv) {
        float s[8];
        unpack8(spk[vv], s);
#pragma unroll
        for (int k = 0; k < 8; ++k) {
            int bit = vv * 8 + k;
            bool posf = (posm >> bit) & 1u;
            bool negf = (negm >> bit) & 1u;
            pl += (posf && s[k] < thr_n) ? 1.f - s[k] : 0.f;
            nl += (negf && s[k] > thr_p) ? s[k] : 0.f;
        }
    }
    float tot = pl + nl;
#pragma unroll
    for (int off = 32; off > 0; off >>= 1) tot += __shfl_xor(tot, off);

    // Chunked scan: 7 bins/thread; shuffle inclusive scan of thread totals.
    // Pack (pos<<32)|all so one u64 scan covers both cumsums (no carry between
    // halves: total all-weight per row = 4095*65536 < 2^32).
    const int CH = 7;
    int base = t * CH;
    unsigned long long lc[CH];
    unsigned long long run = 0ull;
#pragma unroll
    for (int k = 0; k < CH; ++k) {
        int idx = base + k;
        unsigned long long h = (idx < L_BINS)
            ? (((unsigned long long)histP[idx] << 32) | (unsigned long long)histA[idx])
            : 0ull;
        run += h;
        lc[k] = run;
    }
    unsigned long long tsum = run;
    unsigned long long sc = tsum;
#pragma unroll
    for (int off = 1; off < 64; off <<= 1) {
        unsigned long long v2 = __shfl_up(sc, off);
        if (lane >= off) sc += v2;
    }
    if (lane == 63) wsum[w] = sc;
    if (lane == 0) lsum[w] = tot;
    __syncthreads();
    unsigned long long woff = 0ull;
    for (int ww = 0; ww < w; ++ww) woff += wsum[ww];
    unsigned long long throff = woff + sc - tsum;  // exclusive offset for this thread

    float ap = 0.f;
#pragma unroll
    for (int k = 0; k < CH; ++k) {
        int idx = base + k;
        if (idx < L_BINS) {
            unsigned int hp = histP[idx];
            if (hp) {
                unsigned long long cum = lc[k] + throff;
                unsigned int Hp = (unsigned int)(cum >> 32);
                unsigned int Ha = (unsigned int)cum;
                ap += (float)hp * (float)Hp / (float)Ha;
            }
        }
    }
#pragma unroll
    for (int off = 32; off > 0; off >>= 1) {
        ap += __shfl_xor(ap, off);
        npos += __shfl_xor(npos, off);
    }
    if (lane == 0) { apw[w] = ap; npw[w] = npos; }
    __syncthreads();
    if (t == 0) {
        float loss_i = (pmax > -1e30f) ? (lsum[0] + lsum[1] + lsum[2] + lsum[3]) : 0.f;
        float A = apw[0] + apw[1] + apw[2] + apw[3];
        int np = npw[0] + npw[1] + npw[2] + npw[3];
        float reward = (np > 0) ? A * (1.0f / 65536.0f) / (float)np : 0.f;
        contrib[i] = loss_i * (1.f - reward);
    }
}

__global__ __launch_bounds__(256) void final_kernel(const float* __restrict__ contrib,
                                                    float* __restrict__ out, int n) {
    __shared__ float r[256];
    int t = threadIdx.x;
    float s = 0.f;
    for (int j = t; j < n; j += 256) s += contrib[j];
    r[t] = s;
    __syncthreads();
    for (int off = 128; off > 0; off >>= 1) {
        if (t < off) r[t] += r[t + off];
        __syncthreads();
    }
    if (t == 0) out[0] = r[0] / (float)n;
}

extern "C" void kernel_launch(void* const* d_in, const int* in_sizes, int n_in,
                              void* d_out, int out_size, void* d_ws, size_t ws_size,
                              hipStream_t stream) {
    const float* inputs_col = (const float*)d_in[0];
    const int* targets_col = (const int*)d_in[1];
    const float* inputs_row = (const float*)d_in[2];
    const int* targets_row = (const int*)d_in[3];
    const int* reward_labels = (const int*)d_in[4];
    float* out = (float*)d_out;

    const int n = N_ROWS, m = N_ROWS, d = DIM;
    char* ws = (char*)d_ws;
    const size_t MB = 1048576;
    unsigned short* simbuf = (unsigned short*)ws;                 // 32 MB
    unsigned short* grambuf = (unsigned short*)(ws + 32 * MB);    // 32 MB
    unsigned short* Abf = (unsigned short*)(ws + 64 * MB);        // 1 MB
    unsigned short* Rbf = (unsigned short*)(ws + 65 * MB);        // 1 MB
    float* contrib = (float*)(ws + 66 * MB);                      // 16 KB

    // 1) f32 -> bf16 (both arrays, one launch)
    cvt2_kernel<<<512, 256, 0, stream>>>((const float4*)inputs_col, (const float4*)inputs_row,
                                         (ushort4*)Abf, (ushort4*)Rbf, n * d / 4);

    // 2) sim = col@row^T and gram = col@col^T in one launch
    dim3 ggrid(n / TILE, n / TILE, 2);
    gemm_tile_kernel<<<ggrid, 256, 0, stream>>>(Abf, Rbf, Abf, simbuf, grambuf, m);

    // 3) merged per-row loss + FastAP reward -> contrib[i]
    lossap_kernel<<<n, 256, 0, stream>>>(simbuf, grambuf, targets_col, targets_row,
                                         reward_labels, contrib, n);

    // 4) final scalar
    final_kernel<<<1, 256, 0, stream>>>(contrib, out, n);
}